// Round 9
// baseline (256.831 us; speedup 1.0000x reference)
//
#include <hip/hip_runtime.h>

#define NOUT 7
#define NROI 512
#define NCH 256
#define BINS (NOUT * NOUT)        // 49
#define ROI_ELEMS (NCH * BINS)    // 12544
#define CHUNKS (ROI_ELEMS / 256)  // 49 gather chunks per roi

// virtual float4 pyramid sizes
#define S2F4 7782400
#define S3F4 1945600
#define S4F4 486400
#define S5F4 121600
#define TOTF4 (S2F4 + S3F4 + S4F4 + S5F4)   // 10,336,000
#define NSTREAM 512
#define PERBLK ((TOTF4 + NSTREAM - 1) / NSTREAM)   // 20188
#define PERTHR ((PERBLK + 255) / 256)              // 79

// float4 with 4-byte alignment for the gather path
typedef float f4u __attribute__((ext_vector_type(4), aligned(4)));

__global__ __launch_bounds__(256) void roi_pool_kernel(
    const float* __restrict__ x2,
    const float* __restrict__ x3,
    const float* __restrict__ x4,
    const float* __restrict__ x5,
    const float* __restrict__ boxes,
    float* __restrict__ out,
    float* __restrict__ ws)
{
    const int r = blockIdx.x;
    const int t = threadIdx.x;

    // ---- streamer blocks: blockIdx.y == 0, dispatched first (x-fastest) ----
    // Sequentially read the whole pyramid -> fills L3 at streaming efficiency.
    if (blockIdx.y == 0) {
        const float4* const p2 = (const float4*)x2;
        const float4* const p3 = (const float4*)x3;
        const float4* const p4 = (const float4*)x4;
        const float4* const p5 = (const float4*)x5;
        const int start = r * PERBLK;
        float s = 0.0f;
        #pragma unroll 4
        for (int k = 0; k < PERTHR; ++k) {
            const int idx = start + k * 256 + t;
            if (idx < TOTF4) {
                float4 v;
                if (idx < S2F4)                    v = p2[idx];
                else if (idx < S2F4 + S3F4)        v = p3[idx - S2F4];
                else if (idx < S2F4 + S3F4 + S4F4) v = p4[idx - S2F4 - S3F4];
                else                               v = p5[idx - S2F4 - S3F4 - S4F4];
                s += v.x + v.y + v.z + v.w;
            }
        }
        if (t == 0) ws[r] = s;   // defeat DCE; harness never checks ws
        return;
    }

    const int chunk = blockIdx.y - 1;   // 0..48

    // ---- gather path: R7 verbatim ----
    __shared__ float4 sdyA[NOUT];
    __shared__ float2 sdyB[NOUT];
    __shared__ float4 sdxW[NOUT];
    __shared__ int    sdxC[NOUT];
    __shared__ float4 sdxP[NOUT];
    __shared__ float2 sdxQ[NOUT];
    __shared__ int    sfast;
    __shared__ const float* sbase;
    __shared__ int sW, sHW;

    if (t < 32) {
        const float bx1 = boxes[4 * r + 0];
        const float by1 = boxes[4 * r + 1];
        const float bx2 = boxes[4 * r + 2];
        const float by2 = boxes[4 * r + 3];
        const float sz  = sqrtf((bx2 - bx1) * (by2 - by1));
        float lvlf = floorf(4.0f + log2f(sz / 224.0f + 1e-8f));
        lvlf = fminf(fmaxf(lvlf, 2.0f), 5.0f);
        const int level = (int)lvlf - 2;

        int H, W; float scale; const float* feat;
        if (level == 0)      { H = 200; W = 304; scale = 0.25f;    feat = x2; }
        else if (level == 1) { H = 100; W = 152; scale = 0.125f;   feat = x3; }
        else if (level == 2) { H = 50;  W = 76;  scale = 0.0625f;  feat = x4; }
        else                 { H = 25;  W = 38;  scale = 0.03125f; feat = x5; }

        const float X1 = bx1 * scale - 0.5f;
        const float Y1 = by1 * scale - 0.5f;
        const float X2 = bx2 * scale - 0.5f;
        const float Y2 = by2 * scale - 0.5f;
        const float bw = (X2 - X1) * (1.0f / NOUT);
        const float bh = (Y2 - Y1) * (1.0f / NOUT);

        bool okl = true;

        if (t < NOUT) {
            const int ph = t;
            float ca = Y1 + ((float)ph + 0.25f) * bh;
            float cb = Y1 + ((float)ph + 0.75f) * bh;
            const float va = ((ca >= -1.0f) && (ca <= (float)H)) ? 0.25f : 0.0f;
            const float vb = ((cb >= -1.0f) && (cb <= (float)H)) ? 0.25f : 0.0f;
            ca = fminf(fmaxf(ca, 0.0f), (float)(H - 1));
            cb = fminf(fmaxf(cb, 0.0f), (float)(H - 1));
            const int ia = min((int)floorf(ca), H - 2);
            const int ib = min((int)floorf(cb), H - 2);
            const float fya = ca - (float)ia;
            const float fyb = cb - (float)ib;
            sdyA[ph] = make_float4(__int_as_float(ia * W), __int_as_float(ib * W),
                                   va * (1.0f - fya), va * fya);
            sdyB[ph] = make_float2(vb * (1.0f - fyb), vb * fyb);
        } else if (t >= 8 && t < 8 + NOUT) {
            const int pw = t - 8;
            float ca = X1 + ((float)pw + 0.25f) * bw;
            float cb = X1 + ((float)pw + 0.75f) * bw;
            const float va = ((ca >= -1.0f) && (ca <= (float)W)) ? 1.0f : 0.0f;
            const float vb = ((cb >= -1.0f) && (cb <= (float)W)) ? 1.0f : 0.0f;
            ca = fminf(fmaxf(ca, 0.0f), (float)(W - 1));
            cb = fminf(fmaxf(cb, 0.0f), (float)(W - 1));
            const int ia = min((int)floorf(ca), W - 2);
            const int ib = min((int)floorf(cb), W - 2);
            const float fxa = ca - (float)ia;
            const float fxb = cb - (float)ib;

            sdxP[pw] = make_float4(__int_as_float(ia), __int_as_float(ib),
                                   va * (1.0f - fxa), va * fxa);
            sdxQ[pw] = make_float2(vb * (1.0f - fxb), vb * fxb);

            const int xb = min(ia, W - 4);
            const int d0 = ia - xb;
            const int d1 = ib - xb;
            okl = (d1 <= 2);
            float xw[4];
            #pragma unroll
            for (int k = 0; k < 4; ++k) {
                float w = 0.0f;
                w += va * ((k == d0) ? (1.0f - fxa) : (k == d0 + 1) ? fxa : 0.0f);
                w += vb * ((k == d1) ? (1.0f - fxb) : (k == d1 + 1) ? fxb : 0.0f);
                xw[k] = w;
            }
            sdxW[pw] = make_float4(xw[0], xw[1], xw[2], xw[3]);
            sdxC[pw] = xb;
        }

        const unsigned long long bal = __ballot(okl);
        if (t == 31) {
            const int b = r >> 8;
            sbase = feat + (size_t)b * NCH * H * W;
            sW    = W;
            sHW   = H * W;
            sfast = (((bal >> 8) & 0x7Full) == 0x7Full);
        }
    }
    __syncthreads();

    const float* const base = sbase;
    const int W  = sW;
    const int HW = sHW;
    const int fast = sfast;

    const int i   = chunk * 256 + t;
    const int c   = i / BINS;
    const int bin = i - c * BINS;
    const int ph  = bin / NOUT;
    const int pw  = bin - ph * NOUT;

    const float4 yA = sdyA[ph];
    const float2 yB = sdyB[ph];

    const float* const f  = base + (size_t)c * HW;
    const float* const pa = f + __float_as_int(yA.x);
    const float* const pb = f + __float_as_int(yA.y);

    float d0, d1, d2, d3;
    if (fast) {
        const float4 xw = sdxW[pw];
        const int    xb = sdxC[pw];
        const f4u r0 = *(const f4u*)(pa + xb);
        const f4u r1 = *(const f4u*)(pa + W + xb);
        const f4u r2 = *(const f4u*)(pb + xb);
        const f4u r3 = *(const f4u*)(pb + W + xb);
        d0 = r0.x * xw.x + r0.y * xw.y + r0.z * xw.z + r0.w * xw.w;
        d1 = r1.x * xw.x + r1.y * xw.y + r1.z * xw.z + r1.w * xw.w;
        d2 = r2.x * xw.x + r2.y * xw.y + r2.z * xw.z + r2.w * xw.w;
        d3 = r3.x * xw.x + r3.y * xw.y + r3.z * xw.z + r3.w * xw.w;
    } else {
        const float4 xp = sdxP[pw];
        const float2 xq = sdxQ[pw];
        const int ia = __float_as_int(xp.x);
        const int ib = __float_as_int(xp.y);
        const float2 a0 = *(const float2*)(pa + ia);
        const float2 b0 = *(const float2*)(pa + ib);
        const float2 a1 = *(const float2*)(pa + W + ia);
        const float2 b1 = *(const float2*)(pa + W + ib);
        const float2 a2 = *(const float2*)(pb + ia);
        const float2 b2 = *(const float2*)(pb + ib);
        const float2 a3 = *(const float2*)(pb + W + ia);
        const float2 b3 = *(const float2*)(pb + W + ib);
        d0 = a0.x * xp.z + a0.y * xp.w + b0.x * xq.x + b0.y * xq.y;
        d1 = a1.x * xp.z + a1.y * xp.w + b1.x * xq.x + b1.y * xq.y;
        d2 = a2.x * xp.z + a2.y * xp.w + b2.x * xq.x + b2.y * xq.y;
        d3 = a3.x * xp.z + a3.y * xp.w + b3.x * xq.x + b3.y * xq.y;
    }

    const float acc = yA.z * d0 + yA.w * d1 + yB.x * d2 + yB.y * d3;
    out[(size_t)r * ROI_ELEMS + i] = acc;
}

extern "C" void kernel_launch(void* const* d_in, const int* in_sizes, int n_in,
                              void* d_out, int out_size, void* d_ws, size_t ws_size,
                              hipStream_t stream) {
    const float* x2    = (const float*)d_in[0];
    const float* x3    = (const float*)d_in[1];
    const float* x4    = (const float*)d_in[2];
    const float* x5    = (const float*)d_in[3];
    const float* boxes = (const float*)d_in[4];
    float* out = (float*)d_out;
    float* ws  = (float*)d_ws;

    dim3 grid(NROI, CHUNKS + 1);   // y==0: streamer row (dispatched first)
    roi_pool_kernel<<<grid, 256, 0, stream>>>(x2, x3, x4, x5, boxes, out, ws);
}

// Round 10
// 227.601 us; speedup vs baseline: 1.1284x; 1.1284x over previous
//
#include <hip/hip_runtime.h>

#define NOUT 7
#define NROI 512
#define NCH 256
#define BINS (NOUT * NOUT)        // 49
#define ROI_ELEMS (NCH * BINS)    // 12544
#define CHUNKS (ROI_ELEMS / 256)  // 49 chunks of 256 threads per roi

// float4 with 4-byte alignment: dword-aligned but not 16B-aligned loads
// (gfx950 handles this; validated since R3/R7).
typedef float f4u __attribute__((ext_vector_type(4), aligned(4)));

__global__ __launch_bounds__(256) void roi_pool_kernel(
    const float* __restrict__ x2,
    const float* __restrict__ x3,
    const float* __restrict__ x4,
    const float* __restrict__ x5,
    const float* __restrict__ boxes,
    float* __restrict__ out)
{
    // GRID SWAP vs R7: chunk on x (fast dispatch dim), roi on y (slow).
    // Co-resident blocks now cover all channels of ~40 rois instead of a few
    // channels of all 512 -> instantaneous DRAM/L2 footprint ~21 MB not 165 MB.
    const int chunk = blockIdx.x;  // 0..48
    const int r     = blockIdx.y;  // roi 0..511
    const int t     = threadIdx.x; // 0..255

    __shared__ float4 sdyA[NOUT];
    __shared__ float2 sdyB[NOUT];
    __shared__ float4 sdxW[NOUT];
    __shared__ int    sdxC[NOUT];
    __shared__ float4 sdxP[NOUT];
    __shared__ float2 sdxQ[NOUT];
    __shared__ int    sfast;
    __shared__ const float* sbase;
    __shared__ int sW, sHW;

    if (t < 32) {
        const float bx1 = boxes[4 * r + 0];
        const float by1 = boxes[4 * r + 1];
        const float bx2 = boxes[4 * r + 2];
        const float by2 = boxes[4 * r + 3];
        const float sz  = sqrtf((bx2 - bx1) * (by2 - by1));
        float lvlf = floorf(4.0f + log2f(sz / 224.0f + 1e-8f));
        lvlf = fminf(fmaxf(lvlf, 2.0f), 5.0f);
        const int level = (int)lvlf - 2;

        int H, W; float scale; const float* feat;
        if (level == 0)      { H = 200; W = 304; scale = 0.25f;    feat = x2; }
        else if (level == 1) { H = 100; W = 152; scale = 0.125f;   feat = x3; }
        else if (level == 2) { H = 50;  W = 76;  scale = 0.0625f;  feat = x4; }
        else                 { H = 25;  W = 38;  scale = 0.03125f; feat = x5; }

        const float X1 = bx1 * scale - 0.5f;
        const float Y1 = by1 * scale - 0.5f;
        const float X2 = bx2 * scale - 0.5f;
        const float Y2 = by2 * scale - 0.5f;
        const float bw = (X2 - X1) * (1.0f / NOUT);
        const float bh = (Y2 - Y1) * (1.0f / NOUT);

        bool okl = true;   // per-lane fast-path fitness (x lanes only)

        if (t < NOUT) {
            // y descriptors for output row ph = t (samples at ph+0.25, ph+0.75)
            const int ph = t;
            float ca = Y1 + ((float)ph + 0.25f) * bh;
            float cb = Y1 + ((float)ph + 0.75f) * bh;
            const float va = ((ca >= -1.0f) && (ca <= (float)H)) ? 0.25f : 0.0f;
            const float vb = ((cb >= -1.0f) && (cb <= (float)H)) ? 0.25f : 0.0f;
            ca = fminf(fmaxf(ca, 0.0f), (float)(H - 1));
            cb = fminf(fmaxf(cb, 0.0f), (float)(H - 1));
            const int ia = min((int)floorf(ca), H - 2);   // i1 = i0+1 normalization
            const int ib = min((int)floorf(cb), H - 2);
            const float fya = ca - (float)ia;
            const float fyb = cb - (float)ib;
            sdyA[ph] = make_float4(__int_as_float(ia * W), __int_as_float(ib * W),
                                   va * (1.0f - fya), va * fya);
            sdyB[ph] = make_float2(vb * (1.0f - fyb), vb * fyb);
        } else if (t >= 8 && t < 8 + NOUT) {
            // x descriptors for output col pw = t-8
            const int pw = t - 8;
            float ca = X1 + ((float)pw + 0.25f) * bw;
            float cb = X1 + ((float)pw + 0.75f) * bw;
            const float va = ((ca >= -1.0f) && (ca <= (float)W)) ? 1.0f : 0.0f;
            const float vb = ((cb >= -1.0f) && (cb <= (float)W)) ? 1.0f : 0.0f;
            ca = fminf(fmaxf(ca, 0.0f), (float)(W - 1));
            cb = fminf(fmaxf(cb, 0.0f), (float)(W - 1));
            const int ia = min((int)floorf(ca), W - 2);
            const int ib = min((int)floorf(cb), W - 2);
            const float fxa = ca - (float)ia;
            const float fxb = cb - (float)ib;

            // slow-path descriptors (always valid)
            sdxP[pw] = make_float4(__int_as_float(ia), __int_as_float(ib),
                                   va * (1.0f - fxa), va * fxa);
            sdxQ[pw] = make_float2(vb * (1.0f - fxb), vb * fxb);

            // fast-path descriptors (valid iff both patches fit [xb, xb+3])
            const int xb = min(ia, W - 4);
            const int d0 = ia - xb;          // 0..2
            const int d1 = ib - xb;          // >= d0; fast iff <= 2
            okl = (d1 <= 2);
            float xw[4];
            #pragma unroll
            for (int k = 0; k < 4; ++k) {
                float w = 0.0f;
                w += va * ((k == d0) ? (1.0f - fxa) : (k == d0 + 1) ? fxa : 0.0f);
                w += vb * ((k == d1) ? (1.0f - fxb) : (k == d1 + 1) ? fxb : 0.0f);
                xw[k] = w;
            }
            sdxW[pw] = make_float4(xw[0], xw[1], xw[2], xw[3]);
            sdxC[pw] = xb;
        }

        const unsigned long long bal = __ballot(okl);
        if (t == 31) {
            const int b = r >> 8;
            sbase = feat + (size_t)b * NCH * H * W;
            sW    = W;
            sHW   = H * W;
            sfast = (((bal >> 8) & 0x7Full) == 0x7Full);
        }
    }
    __syncthreads();

    const float* const base = sbase;
    const int W  = sW;
    const int HW = sHW;
    const int fast = sfast;

    // one output element per thread
    const int i   = chunk * 256 + t;      // 0..12543 within this roi
    const int c   = i / BINS;             // channel 0..255
    const int bin = i - c * BINS;         // 0..48
    const int ph  = bin / NOUT;
    const int pw  = bin - ph * NOUT;

    const float4 yA = sdyA[ph];
    const float2 yB = sdyB[ph];

    const float* const f  = base + (size_t)c * HW;
    const float* const pa = f + __float_as_int(yA.x);   // row y0a
    const float* const pb = f + __float_as_int(yA.y);   // row y0b

    float d0, d1, d2, d3;
    if (fast) {
        const float4 xw = sdxW[pw];
        const int    xb = sdxC[pw];
        const f4u r0 = *(const f4u*)(pa + xb);
        const f4u r1 = *(const f4u*)(pa + W + xb);
        const f4u r2 = *(const f4u*)(pb + xb);
        const f4u r3 = *(const f4u*)(pb + W + xb);
        d0 = r0.x * xw.x + r0.y * xw.y + r0.z * xw.z + r0.w * xw.w;
        d1 = r1.x * xw.x + r1.y * xw.y + r1.z * xw.z + r1.w * xw.w;
        d2 = r2.x * xw.x + r2.y * xw.y + r2.z * xw.z + r2.w * xw.w;
        d3 = r3.x * xw.x + r3.y * xw.y + r3.z * xw.z + r3.w * xw.w;
    } else {
        const float4 xp = sdxP[pw];
        const float2 xq = sdxQ[pw];
        const int ia = __float_as_int(xp.x);
        const int ib = __float_as_int(xp.y);
        const float2 a0 = *(const float2*)(pa + ia);
        const float2 b0 = *(const float2*)(pa + ib);
        const float2 a1 = *(const float2*)(pa + W + ia);
        const float2 b1 = *(const float2*)(pa + W + ib);
        const float2 a2 = *(const float2*)(pb + ia);
        const float2 b2 = *(const float2*)(pb + ib);
        const float2 a3 = *(const float2*)(pb + W + ia);
        const float2 b3 = *(const float2*)(pb + W + ib);
        d0 = a0.x * xp.z + a0.y * xp.w + b0.x * xq.x + b0.y * xq.y;
        d1 = a1.x * xp.z + a1.y * xp.w + b1.x * xq.x + b1.y * xq.y;
        d2 = a2.x * xp.z + a2.y * xp.w + b2.x * xq.x + b2.y * xq.y;
        d3 = a3.x * xp.z + a3.y * xp.w + b3.x * xq.x + b3.y * xq.y;
    }

    const float acc = yA.z * d0 + yA.w * d1 + yB.x * d2 + yB.y * d3;
    out[(size_t)r * ROI_ELEMS + i] = acc;
}

extern "C" void kernel_launch(void* const* d_in, const int* in_sizes, int n_in,
                              void* d_out, int out_size, void* d_ws, size_t ws_size,
                              hipStream_t stream) {
    const float* x2    = (const float*)d_in[0];
    const float* x3    = (const float*)d_in[1];
    const float* x4    = (const float*)d_in[2];
    const float* x5    = (const float*)d_in[3];
    const float* boxes = (const float*)d_in[4];
    float* out = (float*)d_out;

    dim3 grid(CHUNKS, NROI);   // chunk fast, roi slow
    roi_pool_kernel<<<grid, 256, 0, stream>>>(x2, x3, x4, x5, boxes, out);
}